// Round 16
// baseline (727.655 us; speedup 1.0000x reference)
//
#include <hip/hip_runtime.h>
#include <hip/hip_bf16.h>

namespace {

constexpr int NV = 32000;
constexpr int NE = 256;
constexpr int NH = 512;
constexpr int NB = 32;
constexpr int NT = 64;
constexpr int NG = 3 * NH;    // 1536
constexpr int NM = NB * NT;   // 2048
constexpr int SOS = 1;
constexpr int NTILE = 250;    // NV/128
constexpr int NITEM = 8 * NTILE;
constexpr int NWORK = 232;
constexpr int NV4 = NV / 4;   // 8000

typedef _Float16 f16_t;
typedef _Float16 f16x8 __attribute__((ext_vector_type(8)));
typedef float f32x4 __attribute__((ext_vector_type(4)));

typedef __attribute__((address_space(1))) void gvoid_t;
typedef __attribute__((address_space(3))) void lvoid_t;

union P8 { f16_t h[4]; unsigned long long u; };

// fragment-order offset of h[u][b] inside a 512x32 f16 step buffer.
// B-frag of mfma_f32_16x16x32_f16: lane l holds col n=l&15, k=(l>>4)*8+j.
__device__ __forceinline__ int fragoff(int u, int b) {
  return ((b >> 4) * 16 + (u >> 5)) * 512 +
         ((((u >> 3) & 3) * 16) + (b & 15)) * 8 + (u & 7);
}

__device__ __forceinline__ void load_wf(const float* wrow, f16x8* wf) {
  #pragma unroll
  for (int kc = 0; kc < 16; ++kc) {
    f32x4 a = *(const f32x4*)(wrow + kc * 32);
    f32x4 c = *(const f32x4*)(wrow + kc * 32 + 4);
    f16x8 w;
    w[0] = (f16_t)a[0]; w[1] = (f16_t)a[1]; w[2] = (f16_t)a[2]; w[3] = (f16_t)a[3];
    w[4] = (f16_t)c[0]; w[5] = (f16_t)c[1]; w[6] = (f16_t)c[2]; w[7] = (f16_t)c[3];
    wf[kc] = w;
  }
}

__device__ __forceinline__ float sigm(float x) { return 1.f / (1.f + __expf(-x)); }

// Per-block flag words, each on its own 64B line (int stride 16).
__device__ __forceinline__ void wait_flag(int* p, int target) {
  while (__hip_atomic_load(p, __ATOMIC_RELAXED, __HIP_MEMORY_SCOPE_AGENT) < target)
    __builtin_amdgcn_s_sleep(1);
}

__device__ __forceinline__ int peek_flag(int* p) {
  return __hip_atomic_load(p, __ATOMIC_RELAXED, __HIP_MEMORY_SCOPE_AGENT);
}

// Write-through 8B store (relaxed agent atomic): data visible at coherent point.
__device__ __forceinline__ void store8(void* dst, unsigned long long v) {
  __hip_atomic_store((unsigned long long*)dst, v, __ATOMIC_RELAXED,
                     __HIP_MEMORY_SCOPE_AGENT);
}

// ---------------- mega kernel ----------------
// R16: R15 + XCD role remap (the ONLY change). lg = (bid&7)*32 + (bid>>3)
// puts rnn roles 0..23 on physical bids {0,8,..,184} — all bid%8==0, i.e. ONE
// XCD under round-robin dispatch. The recurrence's h-traffic and flags are
// served by one L2 shared with only 8/232 worker blocks, isolating the latency
// chain from the gemm/lsm streams. Placement heuristic only; correctness rests
// on the agent-scope protocol regardless of mapping.

__global__ __launch_bounds__(768) void k_mega(
    const int* __restrict__ tgt, const float* __restrict__ emb,
    const float* __restrict__ Wih0, const float* __restrict__ bih0,
    f16_t* __restrict__ Gi0,
    const float* __restrict__ Whh0, const float* __restrict__ bhh0,
    const float* __restrict__ Wih1, const float* __restrict__ bih1,
    const float* __restrict__ Whh1, const float* __restrict__ bhh1,
    const float* __restrict__ eh,
    f16_t* __restrict__ hb0, f16_t* __restrict__ hb1,
    f16_t* __restrict__ Abf, float* __restrict__ hfin,
    const float* __restrict__ Wout, const float* __restrict__ bout,
    f16_t* __restrict__ Wf, float* __restrict__ C,
    float* __restrict__ smax, float* __restrict__ ssum,
    int* f0, int* f1, int* cnt, int* wflag, int* initc, int* gfl) {
  __shared__ __align__(16) char pool[49152];
  __shared__ float red[32];
  __shared__ float mW[256], sW[256];
  __shared__ int tks[NB];
  const int tid = threadIdx.x;
  const int wave = tid >> 6, lane = tid & 63;
  const int bid = blockIdx.x;
  const int lg = ((bid & 7) << 5) + (bid >> 3);   // XCD-grouping role remap
  const int eb = tid & 31, eu0 = (tid >> 5) & 15;

  if (lg < 8) {
    // ---------------- layer 0 ----------------
    float* gLDS = (float*)pool;                       // 24 KB
    f16_t* hstage = (f16_t*)(pool + 24576);           // 4 KB
    const int ug = lg * 64;
    const int gate = wave >> 2, tile = wave & 3;
    const int row = gate * 512 + ug + tile * 16 + (lane & 15);
    f16x8 wf[16];
    load_wf(Whh0 + (size_t)row * NH + (lane >> 4) * 8, wf);

    // init: transpose own eh slice into hb0[0] (frag order), publish initc.
    for (int k = tid; k < 512; k += 768) {     // 64u x 32b / 4
      const int u0 = ug + (k & 15) * 4, b = k >> 4;
      P8 p;
      #pragma unroll
      for (int i = 0; i < 4; ++i) p.h[i] = (f16_t)eh[b * NH + u0 + i];
      store8(hb0 + fragoff(u0, b), p.u);
    }
    __syncthreads();
    if (tid == 0) {
      __hip_atomic_fetch_add(initc, 1, __ATOMIC_RELEASE, __HIP_MEMORY_SCOPE_AGENT);
      wait_flag(initc, 24);
    }
    __syncthreads();

    float hprev[4], br[4], bz[4], bn[4];
    if (tid < 512) {
      #pragma unroll
      for (int i = 0; i < 4; ++i) {
        int u = ug + eu0 + i * 16;
        hprev[i] = eh[eb * NH + u];
        br[i] = bhh0[u]; bz[i] = bhh0[512 + u]; bn[i] = bhh0[1024 + u];
      }
    }

    for (int t = 0; t < NT; ++t) {
      if (t > 0 && tid < 8) wait_flag(f0 + tid * 16, t);
      if (tid == 8) wait_flag(gfl + t * 16, 8);   // Gi0[t] ready (workers Phase 0)
      __syncthreads();
      float gr[4], gz[4], gn[4];
      if (tid < 512) {                       // prefetch gi; consumed post-MFMA
        const f16_t* g = Gi0 + (size_t)t * NG * NB;
        #pragma unroll
        for (int i = 0; i < 4; ++i) {
          int u = ug + eu0 + i * 16;
          gr[i] = (float)g[u * NB + eb];
          gz[i] = (float)g[(512 + u) * NB + eb];
          gn[i] = (float)g[(1024 + u) * NB + eb];
        }
      }
      const f16_t* hb = hb0 + (size_t)t * 16384;
      f32x4 acc0 = {0.f, 0.f, 0.f, 0.f}, acc1 = {0.f, 0.f, 0.f, 0.f};
      #pragma unroll
      for (int kc = 0; kc < 16; ++kc) {
        f16x8 b0 = *(const f16x8*)(hb + kc * 512 + lane * 8);
        f16x8 b1 = *(const f16x8*)(hb + (16 + kc) * 512 + lane * 8);
        acc0 = __builtin_amdgcn_mfma_f32_16x16x32_f16(wf[kc], b0, acc0, 0, 0, 0);
        acc1 = __builtin_amdgcn_mfma_f32_16x16x32_f16(wf[kc], b1, acc1, 0, 0, 0);
      }
      {
        const int m0 = (lane >> 4) * 4, col = lane & 15;
        #pragma unroll
        for (int r = 0; r < 4; ++r) {
          int ul = tile * 16 + m0 + r;
          gLDS[(gate * 64 + ul) * 32 + col] = acc0[r];
          gLDS[(gate * 64 + ul) * 32 + 16 + col] = acc1[r];
        }
      }
      __syncthreads();
      if (tid < 512) {
        #pragma unroll
        for (int i = 0; i < 4; ++i) {
          int ul = eu0 + i * 16;
          float rt = gLDS[(0 * 64 + ul) * 32 + eb];
          float zt = gLDS[(1 * 64 + ul) * 32 + eb];
          float nt_ = gLDS[(2 * 64 + ul) * 32 + eb];
          float r = sigm(gr[i] + rt + br[i]);
          float z = sigm(gz[i] + zt + bz[i]);
          float n = tanhf(gn[i] + r * (nt_ + bn[i]));
          float hnew = (1.f - z) * n + z * hprev[i];
          hprev[i] = hnew;
          hstage[((eb >> 4) * 2 + (ul >> 5)) * 512 +
                 ((((ul >> 3) & 3) * 16) + (eb & 15)) * 8 + (ul & 7)] = (f16_t)hnew;
          if (t == NT - 1) hfin[eb * NH + ug + ul] = hnew;
        }
      }
      __syncthreads();
      if (tid < 512) {
        const int chunk = tid >> 7, w = tid & 127;
        const unsigned long long v =
            *(const unsigned long long*)(hstage + chunk * 512 + w * 4);
        store8(hb0 + (size_t)(t + 1) * 16384 +
               ((chunk >> 1) * 16 + (ug >> 5) + (chunk & 1)) * 512 + w * 4, v);
      }
      __syncthreads();
      if (tid == 0)
        __hip_atomic_store(f0 + lg * 16, t + 1, __ATOMIC_RELEASE,
                           __HIP_MEMORY_SCOPE_AGENT);
    }
  } else if (lg < 24) {
    // ---------------- layer 1 (Abf row = t*32+b) ----------------
    float* gLDS = (float*)pool;
    f16_t* hstage = (f16_t*)(pool + 24576);
    f16_t* astage = (f16_t*)(pool + 28672);
    const int g = lg - 8, ug = g * 32;
    const int mm = wave >= 6;                 // 0: Wih1 (x=h0), 1: Whh1 (h1)
    const int w6 = mm ? wave - 6 : wave;
    const int gate = w6 >> 1, tile = w6 & 1;
    const int row = gate * 512 + ug + tile * 16 + (lane & 15);
    const float* W = mm ? Whh1 : Wih1;
    f16x8 wf[16];
    load_wf(W + (size_t)row * NH + (lane >> 4) * 8, wf);

    // init: transpose own eh slice into hb1[0], publish initc.
    for (int k = tid; k < 256; k += 768) {     // 32u x 32b / 4
      const int u0 = ug + (k & 7) * 4, b = k >> 3;
      P8 p;
      #pragma unroll
      for (int i = 0; i < 4; ++i) p.h[i] = (f16_t)eh[16384 + b * NH + u0 + i];
      store8(hb1 + fragoff(u0, b), p.u);
    }
    __syncthreads();
    if (tid == 0) {
      __hip_atomic_fetch_add(initc, 1, __ATOMIC_RELEASE, __HIP_MEMORY_SCOPE_AGENT);
      wait_flag(initc, 24);
    }
    __syncthreads();

    float hprev[2], bir[2], biz[2], bin_[2], bhr[2], bhz[2], bhn[2];
    if (tid < 512) {
      #pragma unroll
      for (int i = 0; i < 2; ++i) {
        int u = ug + eu0 + i * 16;
        hprev[i] = eh[16384 + eb * NH + u];
        bir[i] = bih1[u]; biz[i] = bih1[512 + u]; bin_[i] = bih1[1024 + u];
        bhr[i] = bhh1[u]; bhz[i] = bhh1[512 + u]; bhn[i] = bhh1[1024 + u];
      }
    }

    for (int t = 0; t < NT; ++t) {
      if (tid < 24) {                        // parallel poll: 8x f0, 16x f1
        int* p   = (tid < 8) ? (f0 + tid * 16) : (f1 + (tid - 8) * 16);
        int tgt2 = (tid < 8) ? (t + 1) : t;
        wait_flag(p, tgt2);
      }
      __syncthreads();
      const f16_t* hb = mm ? (hb1 + (size_t)t * 16384)
                           : (hb0 + (size_t)(t + 1) * 16384);
      f32x4 acc0 = {0.f, 0.f, 0.f, 0.f}, acc1 = {0.f, 0.f, 0.f, 0.f};
      #pragma unroll
      for (int kc = 0; kc < 16; ++kc) {
        f16x8 b0 = *(const f16x8*)(hb + kc * 512 + lane * 8);
        f16x8 b1 = *(const f16x8*)(hb + (16 + kc) * 512 + lane * 8);
        acc0 = __builtin_amdgcn_mfma_f32_16x16x32_f16(wf[kc], b0, acc0, 0, 0, 0);
        acc1 = __builtin_amdgcn_mfma_f32_16x16x32_f16(wf[kc], b1, acc1, 0, 0, 0);
      }
      {
        const int m0 = (lane >> 4) * 4, col = lane & 15;
        #pragma unroll
        for (int r = 0; r < 4; ++r) {
          int ul = tile * 16 + m0 + r;
          gLDS[((mm * 3 + gate) * 32 + ul) * 32 + col] = acc0[r];
          gLDS[((mm * 3 + gate) * 32 + ul) * 32 + 16 + col] = acc1[r];
        }
      }
      __syncthreads();
      if (tid < 512) {
        #pragma unroll
        for (int i = 0; i < 2; ++i) {
          int ul = eu0 + i * 16;
          float ir  = gLDS[((0 * 3 + 0) * 32 + ul) * 32 + eb] + bir[i];
          float iz  = gLDS[((0 * 3 + 1) * 32 + ul) * 32 + eb] + biz[i];
          float in_ = gLDS[((0 * 3 + 2) * 32 + ul) * 32 + eb] + bin_[i];
          float hr  = gLDS[((1 * 3 + 0) * 32 + ul) * 32 + eb] + bhr[i];
          float hz  = gLDS[((1 * 3 + 1) * 32 + ul) * 32 + eb] + bhz[i];
          float hn  = gLDS[((1 * 3 + 2) * 32 + ul) * 32 + eb] + bhn[i];
          float r = sigm(ir + hr);
          float z = sigm(iz + hz);
          float n = tanhf(in_ + r * hn);
          float hnew = (1.f - z) * n + z * hprev[i];
          hprev[i] = hnew;
          f16_t hv = (f16_t)hnew;
          hstage[(eb >> 4) * 512 +
                 ((((ul >> 3) & 3) * 16) + (eb & 15)) * 8 + (ul & 7)] = hv;
          astage[eb * 32 + ul] = hv;
          if (t == NT - 1) hfin[16384 + eb * NH + ug + ul] = hnew;
        }
      }
      __syncthreads();
      if (tid < 256) {
        const int chunk = tid >> 7, w = tid & 127;
        const unsigned long long v =
            *(const unsigned long long*)(hstage + chunk * 512 + w * 4);
        store8(hb1 + (size_t)(t + 1) * 16384 + (chunk * 16 + g) * 512 + w * 4, v);
      } else if (tid < 512) {
        const int i2 = tid - 256;                 // 0..255
        const int b = i2 >> 3, uo = (i2 & 7) * 4; // b 0..31, uo 0..28
        store8(Abf + ((size_t)(t * NB + b)) * 512 + ug + uo,   // m = t*32+b
               *(const unsigned long long*)(astage + b * 32 + uo));
      }
      __syncthreads();
      if (tid == 0)
        __hip_atomic_store(f1 + g * 16, t + 1, __ATOMIC_RELEASE,
                           __HIP_MEMORY_SCOPE_AGENT);
    }
  } else {
    // ---------------- workers ----------------
    f16_t* AsB = (f16_t*)pool;             // [2][256*32] = 32 KB
    f16_t* BsB = (f16_t*)(pool + 32768);   // [2][128*32] = 16 KB
    const int wid = lg - 24;               // 0..231
    const int r_in = lane >> 2;
    const int c8 = (lane & 3) * 8;

    // Phase 0: compute Gi0 (fused k_gi0). 512 items = (t, 192-j slab).
    {
      float* xs = (float*)pool;            // [e][b] stride 33, 33.8 KB
      for (int it = wid; it < 512; it += NWORK) {
        const int t = it >> 3, js = (it & 7) * 192;
        if (tid < NB) tks[tid] = (t == 0) ? SOS : tgt[tid * NT + (t - 1)];
        __syncthreads();
        if (tid < NE) {
          #pragma unroll 4
          for (int b = 0; b < NB; ++b) {
            float v = emb[(size_t)tks[b] * NE + tid];
            xs[tid * 33 + b] = v > 0.f ? v : 0.f;
          }
        }
        __syncthreads();
        const int b = tid & 31, jrow = tid >> 5;   // 24 j's x 32 b
        #pragma unroll
        for (int p = 0; p < 8; ++p) {
          const int j = js + p * 24 + jrow;
          float acc = bih0[j];
          const f32x4* wr = (const f32x4*)(Wih0 + (size_t)j * NE);
          #pragma unroll 4
          for (int e4 = 0; e4 < NE / 4; ++e4) {
            f32x4 w = wr[e4];
            acc += w[0] * xs[(4 * e4 + 0) * 33 + b] + w[1] * xs[(4 * e4 + 1) * 33 + b]
                 + w[2] * xs[(4 * e4 + 2) * 33 + b] + w[3] * xs[(4 * e4 + 3) * 33 + b];
          }
          Gi0[((size_t)t * NG + j) * NB + b] = (f16_t)acc;
        }
        __syncthreads();
        if (tid == 0)
          __hip_atomic_fetch_add(gfl + t * 16, 1, __ATOMIC_RELEASE,
                                 __HIP_MEMORY_SCOPE_AGENT);
      }
    }

    // lsm row: merge 250 per-tile (m,s) stats, then ONE apply pass.
    auto lsm_row = [&](int idx) {
      const int t = idx >> 5, b = idx & 31;
      float mt = -3.0e38f, st = 0.f;
      if (tid < NTILE) {
        mt = smax[(size_t)idx * NTILE + tid];
        st = ssum[(size_t)idx * NTILE + tid];
      }
      float m = mt;
      #pragma unroll
      for (int o = 1; o < 64; o <<= 1) m = fmaxf(m, __shfl_xor(m, o, 64));
      if (lane == 0) red[wave] = m;
      __syncthreads();
      m = red[0];
      #pragma unroll
      for (int wv = 1; wv < 12; ++wv) m = fmaxf(m, red[wv]);
      float sc = st * __expf(mt - m);
      #pragma unroll
      for (int o = 1; o < 64; o <<= 1) sc += __shfl_xor(sc, o, 64);
      if (lane == 0) red[16 + wave] = sc;
      __syncthreads();
      float S = 0.f;
      #pragma unroll
      for (int wv = 0; wv < 12; ++wv) S += red[16 + wv];
      const float lse = m + __logf(S);
      f32x4* p4 = (f32x4*)(C + (size_t)(b * 64 + t) * NV);
      for (int i = tid; i < NV4; i += 768) {
        f32x4 v = p4[i];
        v[0] -= lse; v[1] -= lse; v[2] -= lse; v[3] -= lse;
        p4[i] = v;
      }
      __syncthreads();
    };

    // Phase A: convert assigned W_out slabs fp32 -> f16, publish per-slab flag.
    for (int tl = wid; tl < NTILE; tl += NWORK) {
      for (int i = tid; i < 128 * 512 / 8; i += 768) {
        const float* src = Wout + (size_t)tl * 128 * 512 + i * 8;
        f32x4 a = *(const f32x4*)src;
        f32x4 b = *(const f32x4*)(src + 4);
        f16x8 o;
        o[0] = (f16_t)a[0]; o[1] = (f16_t)a[1]; o[2] = (f16_t)a[2]; o[3] = (f16_t)a[3];
        o[4] = (f16_t)b[0]; o[5] = (f16_t)b[1]; o[6] = (f16_t)b[2]; o[7] = (f16_t)b[3];
        *(f16x8*)(Wf + (size_t)tl * 128 * 512 + i * 8) = o;
      }
      __syncthreads();
      if (tid == 0)
        __hip_atomic_store(wflag + tl * 16, 1, __ATOMIC_RELEASE,
                           __HIP_MEMORY_SCOPE_AGENT);
    }

    int lsmIdx = wid;   // next lsm row (global idx, stride NWORK); level = idx>>8

    // Main loop: gemm items by readiness level, interleaved with ready lsm rows.
    for (int item = wid; item < NITEM; item += NWORK) {
      const int mp = item / NTILE, tl = item - mp * NTILE;
      const int m0 = mp * 256;             // rows m = t*32+b, t in [mp*8, mp*8+8)
      const int n0 = tl * 128;
      if (tid < 16) wait_flag(f1 + tid * 16, mp * 8 + 8);
      else if (tid == 16) wait_flag(wflag + tl * 16, 1);
      __syncthreads();

      auto stage = [&](int buf, int kk) {
        if (wave < 8) {                   // A rows: wave*32 .. +32
          const f16_t* Ag = Abf + (size_t)(m0 + wave * 32 + r_in) * NH + kk + c8;
          f16_t* la = AsB + buf * 8192 + (wave * 32) * 32;
          __builtin_amdgcn_global_load_lds((gvoid_t*)Ag, (lvoid_t*)la, 16, 0, 0);
          __builtin_amdgcn_global_load_lds((gvoid_t*)(Ag + 16 * NH),
                                           (lvoid_t*)(la + 16 * 32), 16, 0, 0);
        } else {                          // B rows: (wave-8)*32 .. +32
          const f16_t* Bg = Wf + (size_t)(n0 + (wave - 8) * 32 + r_in) * NH + kk + c8;
          f16_t* lb = BsB + buf * 4096 + ((wave - 8) * 32) * 32;
          __builtin_amdgcn_global_load_lds((gvoid_t*)Bg, (lvoid_t*)lb, 16, 0, 0);
          __builtin_amdgcn_global_load_lds((gvoid_t*)(Bg + 16 * NH),
                                           (lvoid_t*)(lb + 16 * 32), 16, 0, 0);
        }
      };

      f32x4 acc[4][4];
      #pragma unroll
      for (int i = 0; i < 4; ++i)
        #pragma unroll
        for (int j = 0; j < 4; ++j)
          acc[i][j] = (f32x4){0.f, 0.f, 0.f, 0.f};

      const int wm = (wave >> 1) * 64;
      const int wn = (wave & 1) * 64;
      const int arow = lane & 15;
      const int kg = (lane >> 4) * 8;

      stage(0, 0);
      __syncthreads();
      for (int kt = 0; kt < NH / 32; ++kt) {
        const int buf = kt & 1;
        if (kt + 1 < NH / 32) stage(buf ^ 1, (kt + 1) * 32);
        if (wave < 8) {
          f16x8 af[4], bfr[4];
          #pragma unroll
          for (int i = 0; i < 4; ++i) {
            af[i]  = *(const f16x8*)&AsB[buf * 8192 + (wm + i * 16 + arow) * 32 + kg];
            bfr[i] = *(const f16x8*)&BsB[buf * 4096 + (wn + i * 16 + arow) * 32 + kg];
          }
          #pragma unroll
          for (int i = 0; i < 4; ++i)
            #pragma unroll
            for (int j = 0; j < 4; ++j)
              acc[i][j] = __builtin_amdgcn_mfma_f32_16x16x32_f16(af[i], bfr[j],
                                                                 acc[i][j], 0, 0, 0);
        }
        __syncthreads();
      }

      float myM[4][4], myS[4][4];          // per (i,r): row stats over wave's 64 cols
      if (wave < 8) {
        const int crow = (lane >> 4) * 4;
        const int ccol = lane & 15;
        float bb[4];
        #pragma unroll
        for (int j = 0; j < 4; ++j) bb[j] = bout[n0 + wn + j * 16 + ccol];
        #pragma unroll
        for (int j = 0; j < 4; ++j) {
          const int gcol = n0 + wn + j * 16 + ccol;
          #pragma unroll
          for (int i = 0; i < 4; ++i) {
            #pragma unroll
            for (int r = 0; r < 4; ++r) {
              const int am = m0 + wm + i * 16 + crow + r;      // = t*32 + b
              const int orow = (am & 31) * 64 + (am >> 5);     // = b*64 + t
              C[(size_t)orow * NV + gcol] = acc[i][j][r] + bb[j];
            }
          }
        }
        #pragma unroll
        for (int i = 0; i < 4; ++i)
          #pragma unroll
          for (int r = 0; r < 4; ++r) {
            float v0 = acc[i][0][r] + bb[0], v1 = acc[i][1][r] + bb[1];
            float v2 = acc[i][2][r] + bb[2], v3 = acc[i][3][r] + bb[3];
            float mm2 = fmaxf(fmaxf(v0, v1), fmaxf(v2, v3));
            #pragma unroll
            for (int o = 1; o < 16; o <<= 1) mm2 = fmaxf(mm2, __shfl_xor(mm2, o, 64));
            float ss = __expf(v0 - mm2) + __expf(v1 - mm2) +
                       __expf(v2 - mm2) + __expf(v3 - mm2);
            #pragma unroll
            for (int o = 1; o < 16; o <<= 1) ss += __shfl_xor(ss, o, 64);
            myM[i][r] = mm2; myS[i][r] = ss;
          }
      }
      __syncthreads();
      if (wave < 8 && (wave & 1) && (lane & 15) == 0) {   // odd waves stash partials
        #pragma unroll
        for (int i = 0; i < 4; ++i)
          #pragma unroll
          for (int r = 0; r < 4; ++r) {
            int R = wm + i * 16 + (lane >> 4) * 4 + r;
            mW[R] = myM[i][r]; sW[R] = myS[i][r];
          }
      }
      __syncthreads();
      if (wave < 8 && !(wave & 1) && (lane & 15) == 0) {  // even waves combine+write
        #pragma unroll
        for (int i = 0; i < 4; ++i)
          #pragma unroll
          for (int r = 0; r < 4; ++r) {
            int R = wm + i * 16 + (lane >> 4) * 4 + r;
            float mo = mW[R], so = sW[R];
            float me = myM[i][r], se = myS[i][r];
            float M = fmaxf(me, mo);
            float S = se * __expf(me - M) + so * __expf(mo - M);
            int am = m0 + R;
            smax[(size_t)am * NTILE + tl] = M;
            ssum[(size_t)am * NTILE + tl] = S;
          }
      }
      __syncthreads();   // drains C + stats stores before the release RMW
      if (tid == 0)
        __hip_atomic_fetch_add(cnt + mp * 16, 1, __ATOMIC_RELEASE,
                               __HIP_MEMORY_SCOPE_AGENT);

      // Opportunistic NON-BLOCKING lsm drain (fence kept: C reused across replays)
      while (lsmIdx < NM) {
        const int lvl = lsmIdx >> 8;
        if (tid == 0) red[31] = (float)(peek_flag(cnt + lvl * 16) >= NTILE);
        __syncthreads();
        const bool ready = red[31] != 0.f;
        __syncthreads();
        if (!ready) break;
        if (tid == 0) __builtin_amdgcn_fence(__ATOMIC_ACQUIRE, "agent");
        __syncthreads();
        lsm_row(lsmIdx);
        lsmIdx += NWORK;
      }
    }

    // Cleanup: blocking drain of remaining lsm rows (fence kept).
    for (; lsmIdx < NM; lsmIdx += NWORK) {
      const int lvl = lsmIdx >> 8;
      if (tid == 0) {
        wait_flag(cnt + lvl * 16, NTILE);
        __builtin_amdgcn_fence(__ATOMIC_ACQUIRE, "agent");
      }
      __syncthreads();
      lsm_row(lsmIdx);
    }
  }
}

// ws layout (bytes)
constexpr size_t WS_F0  = 0;      // 8 flags, 64B apart
constexpr size_t WS_F1  = 512;    // 16 flags, 64B apart
constexpr size_t WS_CNT = 1536;   // 8 mp counters, 64B apart
constexpr size_t WS_WFL = 2048;   // 250 W-slab flags, 64B apart (ends 18048)
constexpr size_t WS_INI = 18048;  // init counter (own line)
constexpr size_t WS_GFL = 18112;  // 64 per-t Gi0 flags, 64B apart (ends 22208)
constexpr size_t WS_MS0 = 22528;  // memset extent
constexpr size_t WS_GI0 = 22528;
constexpr size_t WS_HB0 = WS_GI0 + sizeof(f16_t) * (size_t)NT * NG * NB;
constexpr size_t WS_HB1 = WS_HB0 + sizeof(f16_t) * (size_t)(NT + 1) * NH * NB;
constexpr size_t WS_ABF = WS_HB1 + sizeof(f16_t) * (size_t)(NT + 1) * NH * NB;
constexpr size_t WS_WF  = WS_ABF + sizeof(f16_t) * (size_t)NM * NH;
constexpr size_t WS_SM  = WS_WF + sizeof(f16_t) * (size_t)NV * NH;
constexpr size_t WS_SS  = WS_SM + sizeof(float) * (size_t)NM * NTILE;

}  // namespace

extern "C" void kernel_launch(void* const* d_in, const int* in_sizes, int n_in,
                              void* d_out, int out_size, void* d_ws, size_t ws_size,
                              hipStream_t stream) {
  const float* enc_h = (const float*)d_in[1];
  const int*   tgt   = (const int*)d_in[2];
  const float* emb   = (const float*)d_in[3];
  const float* Wih0  = (const float*)d_in[4];
  const float* Whh0  = (const float*)d_in[5];
  const float* bih0  = (const float*)d_in[6];
  const float* bhh0  = (const float*)d_in[7];
  const float* Wih1  = (const float*)d_in[8];
  const float* Whh1  = (const float*)d_in[9];
  const float* bih1  = (const float*)d_in[10];
  const float* bhh1  = (const float*)d_in[11];
  const float* Wout  = (const float*)d_in[12];
  const float* bout  = (const float*)d_in[13];

  char* ws = (char*)d_ws;
  int*    f0   = (int*)(ws + WS_F0);
  int*    f1   = (int*)(ws + WS_F1);
  int*    cnt  = (int*)(ws + WS_CNT);
  int*    wfl  = (int*)(ws + WS_WFL);
  int*    ini  = (int*)(ws + WS_INI);
  int*    gfl  = (int*)(ws + WS_GFL);
  f16_t*  Gi0  = (f16_t*)(ws + WS_GI0);
  f16_t*  hb0  = (f16_t*)(ws + WS_HB0);
  f16_t*  hb1  = (f16_t*)(ws + WS_HB1);
  f16_t*  Abf  = (f16_t*)(ws + WS_ABF);
  f16_t*  Wf   = (f16_t*)(ws + WS_WF);
  float*  sm   = (float*)(ws + WS_SM);
  float*  ss   = (float*)(ws + WS_SS);

  float* out  = (float*)d_out;
  float* hfin = out + (size_t)NM * NV;

  hipMemsetAsync(ws, 0, WS_MS0, stream);
  k_mega<<<256, 768, 0, stream>>>(tgt, emb, Wih0, bih0, Gi0,
                                  Whh0, bhh0, Wih1, bih1, Whh1, bhh1,
                                  enc_h, hb0, hb1, Abf, hfin, Wout, bout,
                                  Wf, out, sm, ss, f0, f1, cnt, wfl, ini, gfl);
}

// Round 17
// 708.050 us; speedup vs baseline: 1.0277x; 1.0277x over previous
//
#include <hip/hip_runtime.h>
#include <hip/hip_bf16.h>

namespace {

constexpr int NV = 32000;
constexpr int NE = 256;
constexpr int NH = 512;
constexpr int NB = 32;
constexpr int NT = 64;
constexpr int NG = 3 * NH;    // 1536
constexpr int NM = NB * NT;   // 2048
constexpr int SOS = 1;
constexpr int NTILE = 250;    // NV/128
constexpr int NITEM = 8 * NTILE;
constexpr int NWORK = 232;
constexpr int NV4 = NV / 4;   // 8000

typedef _Float16 f16_t;
typedef _Float16 f16x8 __attribute__((ext_vector_type(8)));
typedef float f32x4 __attribute__((ext_vector_type(4)));

typedef __attribute__((address_space(1))) void gvoid_t;
typedef __attribute__((address_space(3))) void lvoid_t;

union P8 { f16_t h[4]; unsigned long long u; };

// fragment-order offset of h[u][b] inside a 512x32 f16 step buffer.
// B-frag of mfma_f32_16x16x32_f16: lane l holds col n=l&15, k=(l>>4)*8+j.
__device__ __forceinline__ int fragoff(int u, int b) {
  return ((b >> 4) * 16 + (u >> 5)) * 512 +
         ((((u >> 3) & 3) * 16) + (b & 15)) * 8 + (u & 7);
}

__device__ __forceinline__ void load_wf(const float* wrow, f16x8* wf) {
  #pragma unroll
  for (int kc = 0; kc < 16; ++kc) {
    f32x4 a = *(const f32x4*)(wrow + kc * 32);
    f32x4 c = *(const f32x4*)(wrow + kc * 32 + 4);
    f16x8 w;
    w[0] = (f16_t)a[0]; w[1] = (f16_t)a[1]; w[2] = (f16_t)a[2]; w[3] = (f16_t)a[3];
    w[4] = (f16_t)c[0]; w[5] = (f16_t)c[1]; w[6] = (f16_t)c[2]; w[7] = (f16_t)c[3];
    wf[kc] = w;
  }
}

__device__ __forceinline__ float sigm(float x) { return 1.f / (1.f + __expf(-x)); }

// Per-block flag words, each on its own 64B line (int stride 16).
__device__ __forceinline__ void wait_flag(int* p, int target) {
  while (__hip_atomic_load(p, __ATOMIC_RELAXED, __HIP_MEMORY_SCOPE_AGENT) < target)
    __builtin_amdgcn_s_sleep(1);
}

__device__ __forceinline__ int peek_flag(int* p) {
  return __hip_atomic_load(p, __ATOMIC_RELAXED, __HIP_MEMORY_SCOPE_AGENT);
}

// Write-through 8B store (relaxed agent atomic): data visible at coherent point.
__device__ __forceinline__ void store8(void* dst, unsigned long long v) {
  __hip_atomic_store((unsigned long long*)dst, v, __ATOMIC_RELAXED,
                     __HIP_MEMORY_SCOPE_AGENT);
}

// ---------------- mega kernel ----------------
// R17 = R15 exactly (the 710us optimum; R16's XCD remap regressed and is
// reverted). Single launch: rnn blocks 0..23 (R7-proven protocol), workers
// 24..255 run Phase0 (Gi0) -> PhaseA (W cvt) -> gemm items (level-ordered,
// interleaved with opportunistic lsm drain) -> lsm cleanup.

__global__ __launch_bounds__(768) void k_mega(
    const int* __restrict__ tgt, const float* __restrict__ emb,
    const float* __restrict__ Wih0, const float* __restrict__ bih0,
    f16_t* __restrict__ Gi0,
    const float* __restrict__ Whh0, const float* __restrict__ bhh0,
    const float* __restrict__ Wih1, const float* __restrict__ bih1,
    const float* __restrict__ Whh1, const float* __restrict__ bhh1,
    const float* __restrict__ eh,
    f16_t* __restrict__ hb0, f16_t* __restrict__ hb1,
    f16_t* __restrict__ Abf, float* __restrict__ hfin,
    const float* __restrict__ Wout, const float* __restrict__ bout,
    f16_t* __restrict__ Wf, float* __restrict__ C,
    float* __restrict__ smax, float* __restrict__ ssum,
    int* f0, int* f1, int* cnt, int* wflag, int* initc, int* gfl) {
  __shared__ __align__(16) char pool[49152];
  __shared__ float red[32];
  __shared__ float mW[256], sW[256];
  __shared__ int tks[NB];
  const int tid = threadIdx.x;
  const int wave = tid >> 6, lane = tid & 63;
  const int bid = blockIdx.x;
  const int eb = tid & 31, eu0 = (tid >> 5) & 15;

  if (bid < 8) {
    // ---------------- layer 0 ----------------
    float* gLDS = (float*)pool;                       // 24 KB
    f16_t* hstage = (f16_t*)(pool + 24576);           // 4 KB
    const int ug = bid * 64;
    const int gate = wave >> 2, tile = wave & 3;
    const int row = gate * 512 + ug + tile * 16 + (lane & 15);
    f16x8 wf[16];
    load_wf(Whh0 + (size_t)row * NH + (lane >> 4) * 8, wf);

    // init: transpose own eh slice into hb0[0] (frag order), publish initc.
    for (int k = tid; k < 512; k += 768) {     // 64u x 32b / 4
      const int u0 = ug + (k & 15) * 4, b = k >> 4;
      P8 p;
      #pragma unroll
      for (int i = 0; i < 4; ++i) p.h[i] = (f16_t)eh[b * NH + u0 + i];
      store8(hb0 + fragoff(u0, b), p.u);
    }
    __syncthreads();
    if (tid == 0) {
      __hip_atomic_fetch_add(initc, 1, __ATOMIC_RELEASE, __HIP_MEMORY_SCOPE_AGENT);
      wait_flag(initc, 24);
    }
    __syncthreads();

    float hprev[4], br[4], bz[4], bn[4];
    if (tid < 512) {
      #pragma unroll
      for (int i = 0; i < 4; ++i) {
        int u = ug + eu0 + i * 16;
        hprev[i] = eh[eb * NH + u];
        br[i] = bhh0[u]; bz[i] = bhh0[512 + u]; bn[i] = bhh0[1024 + u];
      }
    }

    for (int t = 0; t < NT; ++t) {
      if (t > 0 && tid < 8) wait_flag(f0 + tid * 16, t);
      if (tid == 8) wait_flag(gfl + t * 16, 8);   // Gi0[t] ready (workers Phase 0)
      __syncthreads();
      float gr[4], gz[4], gn[4];
      if (tid < 512) {                       // prefetch gi; consumed post-MFMA
        const f16_t* g = Gi0 + (size_t)t * NG * NB;
        #pragma unroll
        for (int i = 0; i < 4; ++i) {
          int u = ug + eu0 + i * 16;
          gr[i] = (float)g[u * NB + eb];
          gz[i] = (float)g[(512 + u) * NB + eb];
          gn[i] = (float)g[(1024 + u) * NB + eb];
        }
      }
      const f16_t* hb = hb0 + (size_t)t * 16384;
      f32x4 acc0 = {0.f, 0.f, 0.f, 0.f}, acc1 = {0.f, 0.f, 0.f, 0.f};
      #pragma unroll
      for (int kc = 0; kc < 16; ++kc) {
        f16x8 b0 = *(const f16x8*)(hb + kc * 512 + lane * 8);
        f16x8 b1 = *(const f16x8*)(hb + (16 + kc) * 512 + lane * 8);
        acc0 = __builtin_amdgcn_mfma_f32_16x16x32_f16(wf[kc], b0, acc0, 0, 0, 0);
        acc1 = __builtin_amdgcn_mfma_f32_16x16x32_f16(wf[kc], b1, acc1, 0, 0, 0);
      }
      {
        const int m0 = (lane >> 4) * 4, col = lane & 15;
        #pragma unroll
        for (int r = 0; r < 4; ++r) {
          int ul = tile * 16 + m0 + r;
          gLDS[(gate * 64 + ul) * 32 + col] = acc0[r];
          gLDS[(gate * 64 + ul) * 32 + 16 + col] = acc1[r];
        }
      }
      __syncthreads();
      if (tid < 512) {
        #pragma unroll
        for (int i = 0; i < 4; ++i) {
          int ul = eu0 + i * 16;
          float rt = gLDS[(0 * 64 + ul) * 32 + eb];
          float zt = gLDS[(1 * 64 + ul) * 32 + eb];
          float nt_ = gLDS[(2 * 64 + ul) * 32 + eb];
          float r = sigm(gr[i] + rt + br[i]);
          float z = sigm(gz[i] + zt + bz[i]);
          float n = tanhf(gn[i] + r * (nt_ + bn[i]));
          float hnew = (1.f - z) * n + z * hprev[i];
          hprev[i] = hnew;
          hstage[((eb >> 4) * 2 + (ul >> 5)) * 512 +
                 ((((ul >> 3) & 3) * 16) + (eb & 15)) * 8 + (ul & 7)] = (f16_t)hnew;
          if (t == NT - 1) hfin[eb * NH + ug + ul] = hnew;
        }
      }
      __syncthreads();
      if (tid < 512) {
        const int chunk = tid >> 7, w = tid & 127;
        const unsigned long long v =
            *(const unsigned long long*)(hstage + chunk * 512 + w * 4);
        store8(hb0 + (size_t)(t + 1) * 16384 +
               ((chunk >> 1) * 16 + (ug >> 5) + (chunk & 1)) * 512 + w * 4, v);
      }
      __syncthreads();
      if (tid == 0)
        __hip_atomic_store(f0 + bid * 16, t + 1, __ATOMIC_RELEASE,
                           __HIP_MEMORY_SCOPE_AGENT);
    }
  } else if (bid < 24) {
    // ---------------- layer 1 (Abf row = t*32+b) ----------------
    float* gLDS = (float*)pool;
    f16_t* hstage = (f16_t*)(pool + 24576);
    f16_t* astage = (f16_t*)(pool + 28672);
    const int g = bid - 8, ug = g * 32;
    const int mm = wave >= 6;                 // 0: Wih1 (x=h0), 1: Whh1 (h1)
    const int w6 = mm ? wave - 6 : wave;
    const int gate = w6 >> 1, tile = w6 & 1;
    const int row = gate * 512 + ug + tile * 16 + (lane & 15);
    const float* W = mm ? Whh1 : Wih1;
    f16x8 wf[16];
    load_wf(W + (size_t)row * NH + (lane >> 4) * 8, wf);

    // init: transpose own eh slice into hb1[0], publish initc.
    for (int k = tid; k < 256; k += 768) {     // 32u x 32b / 4
      const int u0 = ug + (k & 7) * 4, b = k >> 3;
      P8 p;
      #pragma unroll
      for (int i = 0; i < 4; ++i) p.h[i] = (f16_t)eh[16384 + b * NH + u0 + i];
      store8(hb1 + fragoff(u0, b), p.u);
    }
    __syncthreads();
    if (tid == 0) {
      __hip_atomic_fetch_add(initc, 1, __ATOMIC_RELEASE, __HIP_MEMORY_SCOPE_AGENT);
      wait_flag(initc, 24);
    }
    __syncthreads();

    float hprev[2], bir[2], biz[2], bin_[2], bhr[2], bhz[2], bhn[2];
    if (tid < 512) {
      #pragma unroll
      for (int i = 0; i < 2; ++i) {
        int u = ug + eu0 + i * 16;
        hprev[i] = eh[16384 + eb * NH + u];
        bir[i] = bih1[u]; biz[i] = bih1[512 + u]; bin_[i] = bih1[1024 + u];
        bhr[i] = bhh1[u]; bhz[i] = bhh1[512 + u]; bhn[i] = bhh1[1024 + u];
      }
    }

    for (int t = 0; t < NT; ++t) {
      if (tid < 24) {                        // parallel poll: 8x f0, 16x f1
        int* p   = (tid < 8) ? (f0 + tid * 16) : (f1 + (tid - 8) * 16);
        int tgt2 = (tid < 8) ? (t + 1) : t;
        wait_flag(p, tgt2);
      }
      __syncthreads();
      const f16_t* hb = mm ? (hb1 + (size_t)t * 16384)
                           : (hb0 + (size_t)(t + 1) * 16384);
      f32x4 acc0 = {0.f, 0.f, 0.f, 0.f}, acc1 = {0.f, 0.f, 0.f, 0.f};
      #pragma unroll
      for (int kc = 0; kc < 16; ++kc) {
        f16x8 b0 = *(const f16x8*)(hb + kc * 512 + lane * 8);
        f16x8 b1 = *(const f16x8*)(hb + (16 + kc) * 512 + lane * 8);
        acc0 = __builtin_amdgcn_mfma_f32_16x16x32_f16(wf[kc], b0, acc0, 0, 0, 0);
        acc1 = __builtin_amdgcn_mfma_f32_16x16x32_f16(wf[kc], b1, acc1, 0, 0, 0);
      }
      {
        const int m0 = (lane >> 4) * 4, col = lane & 15;
        #pragma unroll
        for (int r = 0; r < 4; ++r) {
          int ul = tile * 16 + m0 + r;
          gLDS[((mm * 3 + gate) * 32 + ul) * 32 + col] = acc0[r];
          gLDS[((mm * 3 + gate) * 32 + ul) * 32 + 16 + col] = acc1[r];
        }
      }
      __syncthreads();
      if (tid < 512) {
        #pragma unroll
        for (int i = 0; i < 2; ++i) {
          int ul = eu0 + i * 16;
          float ir  = gLDS[((0 * 3 + 0) * 32 + ul) * 32 + eb] + bir[i];
          float iz  = gLDS[((0 * 3 + 1) * 32 + ul) * 32 + eb] + biz[i];
          float in_ = gLDS[((0 * 3 + 2) * 32 + ul) * 32 + eb] + bin_[i];
          float hr  = gLDS[((1 * 3 + 0) * 32 + ul) * 32 + eb] + bhr[i];
          float hz  = gLDS[((1 * 3 + 1) * 32 + ul) * 32 + eb] + bhz[i];
          float hn  = gLDS[((1 * 3 + 2) * 32 + ul) * 32 + eb] + bhn[i];
          float r = sigm(ir + hr);
          float z = sigm(iz + hz);
          float n = tanhf(in_ + r * hn);
          float hnew = (1.f - z) * n + z * hprev[i];
          hprev[i] = hnew;
          f16_t hv = (f16_t)hnew;
          hstage[(eb >> 4) * 512 +
                 ((((ul >> 3) & 3) * 16) + (eb & 15)) * 8 + (ul & 7)] = hv;
          astage[eb * 32 + ul] = hv;
          if (t == NT - 1) hfin[16384 + eb * NH + ug + ul] = hnew;
        }
      }
      __syncthreads();
      if (tid < 256) {
        const int chunk = tid >> 7, w = tid & 127;
        const unsigned long long v =
            *(const unsigned long long*)(hstage + chunk * 512 + w * 4);
        store8(hb1 + (size_t)(t + 1) * 16384 + (chunk * 16 + g) * 512 + w * 4, v);
      } else if (tid < 512) {
        const int i2 = tid - 256;                 // 0..255
        const int b = i2 >> 3, uo = (i2 & 7) * 4; // b 0..31, uo 0..28
        store8(Abf + ((size_t)(t * NB + b)) * 512 + ug + uo,   // m = t*32+b
               *(const unsigned long long*)(astage + b * 32 + uo));
      }
      __syncthreads();
      if (tid == 0)
        __hip_atomic_store(f1 + g * 16, t + 1, __ATOMIC_RELEASE,
                           __HIP_MEMORY_SCOPE_AGENT);
    }
  } else {
    // ---------------- workers ----------------
    f16_t* AsB = (f16_t*)pool;             // [2][256*32] = 32 KB
    f16_t* BsB = (f16_t*)(pool + 32768);   // [2][128*32] = 16 KB
    const int wid = bid - 24;              // 0..231
    const int r_in = lane >> 2;
    const int c8 = (lane & 3) * 8;

    // Phase 0: compute Gi0 (fused k_gi0). 512 items = (t, 192-j slab).
    {
      float* xs = (float*)pool;            // [e][b] stride 33, 33.8 KB
      for (int it = wid; it < 512; it += NWORK) {
        const int t = it >> 3, js = (it & 7) * 192;
        if (tid < NB) tks[tid] = (t == 0) ? SOS : tgt[tid * NT + (t - 1)];
        __syncthreads();
        if (tid < NE) {
          #pragma unroll 4
          for (int b = 0; b < NB; ++b) {
            float v = emb[(size_t)tks[b] * NE + tid];
            xs[tid * 33 + b] = v > 0.f ? v : 0.f;
          }
        }
        __syncthreads();
        const int b = tid & 31, jrow = tid >> 5;   // 24 j's x 32 b
        #pragma unroll
        for (int p = 0; p < 8; ++p) {
          const int j = js + p * 24 + jrow;
          float acc = bih0[j];
          const f32x4* wr = (const f32x4*)(Wih0 + (size_t)j * NE);
          #pragma unroll 4
          for (int e4 = 0; e4 < NE / 4; ++e4) {
            f32x4 w = wr[e4];
            acc += w[0] * xs[(4 * e4 + 0) * 33 + b] + w[1] * xs[(4 * e4 + 1) * 33 + b]
                 + w[2] * xs[(4 * e4 + 2) * 33 + b] + w[3] * xs[(4 * e4 + 3) * 33 + b];
          }
          Gi0[((size_t)t * NG + j) * NB + b] = (f16_t)acc;
        }
        __syncthreads();
        if (tid == 0)
          __hip_atomic_fetch_add(gfl + t * 16, 1, __ATOMIC_RELEASE,
                                 __HIP_MEMORY_SCOPE_AGENT);
      }
    }

    // lsm row: merge 250 per-tile (m,s) stats, then ONE apply pass.
    auto lsm_row = [&](int idx) {
      const int t = idx >> 5, b = idx & 31;
      float mt = -3.0e38f, st = 0.f;
      if (tid < NTILE) {
        mt = smax[(size_t)idx * NTILE + tid];
        st = ssum[(size_t)idx * NTILE + tid];
      }
      float m = mt;
      #pragma unroll
      for (int o = 1; o < 64; o <<= 1) m = fmaxf(m, __shfl_xor(m, o, 64));
      if (lane == 0) red[wave] = m;
      __syncthreads();
      m = red[0];
      #pragma unroll
      for (int wv = 1; wv < 12; ++wv) m = fmaxf(m, red[wv]);
      float sc = st * __expf(mt - m);
      #pragma unroll
      for (int o = 1; o < 64; o <<= 1) sc += __shfl_xor(sc, o, 64);
      if (lane == 0) red[16 + wave] = sc;
      __syncthreads();
      float S = 0.f;
      #pragma unroll
      for (int wv = 0; wv < 12; ++wv) S += red[16 + wv];
      const float lse = m + __logf(S);
      f32x4* p4 = (f32x4*)(C + (size_t)(b * 64 + t) * NV);
      for (int i = tid; i < NV4; i += 768) {
        f32x4 v = p4[i];
        v[0] -= lse; v[1] -= lse; v[2] -= lse; v[3] -= lse;
        p4[i] = v;
      }
      __syncthreads();
    };

    // Phase A: convert assigned W_out slabs fp32 -> f16, publish per-slab flag.
    for (int tl = wid; tl < NTILE; tl += NWORK) {
      for (int i = tid; i < 128 * 512 / 8; i += 768) {
        const float* src = Wout + (size_t)tl * 128 * 512 + i * 8;
        f32x4 a = *(const f32x4*)src;
        f32x4 b = *(const f32x4*)(src + 4);
        f16x8 o;
        o[0] = (f16_t)a[0]; o[1] = (f16_t)a[1]; o[2] = (f16_t)a[2]; o[3] = (f16_t)a[3];
        o[4] = (f16_t)b[0]; o[5] = (f16_t)b[1]; o[6] = (f16_t)b[2]; o[7] = (f16_t)b[3];
        *(f16x8*)(Wf + (size_t)tl * 128 * 512 + i * 8) = o;
      }
      __syncthreads();
      if (tid == 0)
        __hip_atomic_store(wflag + tl * 16, 1, __ATOMIC_RELEASE,
                           __HIP_MEMORY_SCOPE_AGENT);
    }

    int lsmIdx = wid;   // next lsm row (global idx, stride NWORK); level = idx>>8

    // Main loop: gemm items by readiness level, interleaved with ready lsm rows.
    for (int item = wid; item < NITEM; item += NWORK) {
      const int mp = item / NTILE, tl = item - mp * NTILE;
      const int m0 = mp * 256;             // rows m = t*32+b, t in [mp*8, mp*8+8)
      const int n0 = tl * 128;
      if (tid < 16) wait_flag(f1 + tid * 16, mp * 8 + 8);
      else if (tid == 16) wait_flag(wflag + tl * 16, 1);
      __syncthreads();

      auto stage = [&](int buf, int kk) {
        if (wave < 8) {                   // A rows: wave*32 .. +32
          const f16_t* Ag = Abf + (size_t)(m0 + wave * 32 + r_in) * NH + kk + c8;
          f16_t* la = AsB + buf * 8192 + (wave * 32) * 32;
          __builtin_amdgcn_global_load_lds((gvoid_t*)Ag, (lvoid_t*)la, 16, 0, 0);
          __builtin_amdgcn_global_load_lds((gvoid_t*)(Ag + 16 * NH),
                                           (lvoid_t*)(la + 16 * 32), 16, 0, 0);
        } else {                          // B rows: (wave-8)*32 .. +32
          const f16_t* Bg = Wf + (size_t)(n0 + (wave - 8) * 32 + r_in) * NH + kk + c8;
          f16_t* lb = BsB + buf * 4096 + ((wave - 8) * 32) * 32;
          __builtin_amdgcn_global_load_lds((gvoid_t*)Bg, (lvoid_t*)lb, 16, 0, 0);
          __builtin_amdgcn_global_load_lds((gvoid_t*)(Bg + 16 * NH),
                                           (lvoid_t*)(lb + 16 * 32), 16, 0, 0);
        }
      };

      f32x4 acc[4][4];
      #pragma unroll
      for (int i = 0; i < 4; ++i)
        #pragma unroll
        for (int j = 0; j < 4; ++j)
          acc[i][j] = (f32x4){0.f, 0.f, 0.f, 0.f};

      const int wm = (wave >> 1) * 64;
      const int wn = (wave & 1) * 64;
      const int arow = lane & 15;
      const int kg = (lane >> 4) * 8;

      stage(0, 0);
      __syncthreads();
      for (int kt = 0; kt < NH / 32; ++kt) {
        const int buf = kt & 1;
        if (kt + 1 < NH / 32) stage(buf ^ 1, (kt + 1) * 32);
        if (wave < 8) {
          f16x8 af[4], bfr[4];
          #pragma unroll
          for (int i = 0; i < 4; ++i) {
            af[i]  = *(const f16x8*)&AsB[buf * 8192 + (wm + i * 16 + arow) * 32 + kg];
            bfr[i] = *(const f16x8*)&BsB[buf * 4096 + (wn + i * 16 + arow) * 32 + kg];
          }
          #pragma unroll
          for (int i = 0; i < 4; ++i)
            #pragma unroll
            for (int j = 0; j < 4; ++j)
              acc[i][j] = __builtin_amdgcn_mfma_f32_16x16x32_f16(af[i], bfr[j],
                                                                 acc[i][j], 0, 0, 0);
        }
        __syncthreads();
      }

      float myM[4][4], myS[4][4];          // per (i,r): row stats over wave's 64 cols
      if (wave < 8) {
        const int crow = (lane >> 4) * 4;
        const int ccol = lane & 15;
        float bb[4];
        #pragma unroll
        for (int j = 0; j < 4; ++j) bb[j] = bout[n0 + wn + j * 16 + ccol];
        #pragma unroll
        for (int j = 0; j < 4; ++j) {
          const int gcol = n0 + wn + j * 16 + ccol;
          #pragma unroll
          for (int i = 0; i < 4; ++i) {
            #pragma unroll
            for (int r = 0; r < 4; ++r) {
              const int am = m0 + wm + i * 16 + crow + r;      // = t*32 + b
              const int orow = (am & 31) * 64 + (am >> 5);     // = b*64 + t
              C[(size_t)orow * NV + gcol] = acc[i][j][r] + bb[j];
            }
          }
        }
        #pragma unroll
        for (int i = 0; i < 4; ++i)
          #pragma unroll
          for (int r = 0; r < 4; ++r) {
            float v0 = acc[i][0][r] + bb[0], v1 = acc[i][1][r] + bb[1];
            float v2 = acc[i][2][r] + bb[2], v3 = acc[i][3][r] + bb[3];
            float mm2 = fmaxf(fmaxf(v0, v1), fmaxf(v2, v3));
            #pragma unroll
            for (int o = 1; o < 16; o <<= 1) mm2 = fmaxf(mm2, __shfl_xor(mm2, o, 64));
            float ss = __expf(v0 - mm2) + __expf(v1 - mm2) +
                       __expf(v2 - mm2) + __expf(v3 - mm2);
            #pragma unroll
            for (int o = 1; o < 16; o <<= 1) ss += __shfl_xor(ss, o, 64);
            myM[i][r] = mm2; myS[i][r] = ss;
          }
      }
      __syncthreads();
      if (wave < 8 && (wave & 1) && (lane & 15) == 0) {   // odd waves stash partials
        #pragma unroll
        for (int i = 0; i < 4; ++i)
          #pragma unroll
          for (int r = 0; r < 4; ++r) {
            int R = wm + i * 16 + (lane >> 4) * 4 + r;
            mW[R] = myM[i][r]; sW[R] = myS[i][r];
          }
      }
      __syncthreads();
      if (wave < 8 && !(wave & 1) && (lane & 15) == 0) {  // even waves combine+write
        #pragma unroll
        for (int i = 0; i < 4; ++i)
          #pragma unroll
          for (int r = 0; r < 4; ++r) {
            int R = wm + i * 16 + (lane >> 4) * 4 + r;
            float mo = mW[R], so = sW[R];
            float me = myM[i][r], se = myS[i][r];
            float M = fmaxf(me, mo);
            float S = se * __expf(me - M) + so * __expf(mo - M);
            int am = m0 + R;
            smax[(size_t)am * NTILE + tl] = M;
            ssum[(size_t)am * NTILE + tl] = S;
          }
      }
      __syncthreads();   // drains C + stats stores before the release RMW
      if (tid == 0)
        __hip_atomic_fetch_add(cnt + mp * 16, 1, __ATOMIC_RELEASE,
                               __HIP_MEMORY_SCOPE_AGENT);

      // Opportunistic NON-BLOCKING lsm drain (fence kept: C reused across replays)
      while (lsmIdx < NM) {
        const int lvl = lsmIdx >> 8;
        if (tid == 0) red[31] = (float)(peek_flag(cnt + lvl * 16) >= NTILE);
        __syncthreads();
        const bool ready = red[31] != 0.f;
        __syncthreads();
        if (!ready) break;
        if (tid == 0) __builtin_amdgcn_fence(__ATOMIC_ACQUIRE, "agent");
        __syncthreads();
        lsm_row(lsmIdx);
        lsmIdx += NWORK;
      }
    }

    // Cleanup: blocking drain of remaining lsm rows (fence kept).
    for (; lsmIdx < NM; lsmIdx += NWORK) {
      const int lvl = lsmIdx >> 8;
      if (tid == 0) {
        wait_flag(cnt + lvl * 16, NTILE);
        __builtin_amdgcn_fence(__ATOMIC_ACQUIRE, "agent");
      }
      __syncthreads();
      lsm_row(lsmIdx);
    }
  }
}

// ws layout (bytes)
constexpr size_t WS_F0  = 0;      // 8 flags, 64B apart
constexpr size_t WS_F1  = 512;    // 16 flags, 64B apart
constexpr size_t WS_CNT = 1536;   // 8 mp counters, 64B apart
constexpr size_t WS_WFL = 2048;   // 250 W-slab flags, 64B apart (ends 18048)
constexpr size_t WS_INI = 18048;  // init counter (own line)
constexpr size_t WS_GFL = 18112;  // 64 per-t Gi0 flags, 64B apart (ends 22208)
constexpr size_t WS_MS0 = 22528;  // memset extent
constexpr size_t WS_GI0 = 22528;
constexpr size_t WS_HB0 = WS_GI0 + sizeof(f16_t) * (size_t)NT * NG * NB;
constexpr size_t WS_HB1 = WS_HB0 + sizeof(f16_t) * (size_t)(NT + 1) * NH * NB;
constexpr size_t WS_ABF = WS_HB1 + sizeof(f16_t) * (size_t)(NT + 1) * NH * NB;
constexpr size_t WS_WF  = WS_ABF + sizeof(f16_t) * (size_t)NM * NH;
constexpr size_t WS_SM  = WS_WF + sizeof(f16_t) * (size_t)NV * NH;
constexpr size_t WS_SS  = WS_SM + sizeof(float) * (size_t)NM * NTILE;

}  // namespace

extern "C" void kernel_launch(void* const* d_in, const int* in_sizes, int n_in,
                              void* d_out, int out_size, void* d_ws, size_t ws_size,
                              hipStream_t stream) {
  const float* enc_h = (const float*)d_in[1];
  const int*   tgt   = (const int*)d_in[2];
  const float* emb   = (const float*)d_in[3];
  const float* Wih0  = (const float*)d_in[4];
  const float* Whh0  = (const float*)d_in[5];
  const float* bih0  = (const float*)d_in[6];
  const float* bhh0  = (const float*)d_in[7];
  const float* Wih1  = (const float*)d_in[8];
  const float* Whh1  = (const float*)d_in[9];
  const float* bih1  = (const float*)d_in[10];
  const float* bhh1  = (const float*)d_in[11];
  const float* Wout  = (const float*)d_in[12];
  const float* bout  = (const float*)d_in[13];

  char* ws = (char*)d_ws;
  int*    f0   = (int*)(ws + WS_F0);
  int*    f1   = (int*)(ws + WS_F1);
  int*    cnt  = (int*)(ws + WS_CNT);
  int*    wfl  = (int*)(ws + WS_WFL);
  int*    ini  = (int*)(ws + WS_INI);
  int*    gfl  = (int*)(ws + WS_GFL);
  f16_t*  Gi0  = (f16_t*)(ws + WS_GI0);
  f16_t*  hb0  = (f16_t*)(ws + WS_HB0);
  f16_t*  hb1  = (f16_t*)(ws + WS_HB1);
  f16_t*  Abf  = (f16_t*)(ws + WS_ABF);
  f16_t*  Wf   = (f16_t*)(ws + WS_WF);
  float*  sm   = (float*)(ws + WS_SM);
  float*  ss   = (float*)(ws + WS_SS);

  float* out  = (float*)d_out;
  float* hfin = out + (size_t)NM * NV;

  hipMemsetAsync(ws, 0, WS_MS0, stream);
  k_mega<<<256, 768, 0, stream>>>(tgt, emb, Wih0, bih0, Gi0,
                                  Whh0, bhh0, Wih1, bih1, Whh1, bhh1,
                                  enc_h, hb0, hb1, Abf, hfin, Wout, bout,
                                  Wf, out, sm, ss, f0, f1, cnt, wfl, ini, gfl);
}